// Round 2
// baseline (408.729 us; speedup 1.0000x reference)
//
#include <hip/hip_runtime.h>

namespace {

constexpr int BATCH = 256;
constexpr int DCAPS = 10;
constexpr int PCAPS = 1152;
constexpr int ODIM  = 16;
constexpr int IDIM  = 8;
constexpr float EPS_ = 1e-7f;

constexpr int SPLIT  = 8;              // P-chunks (also partial-sum count)
constexpr int PCHUNK = PCAPS / SPLIT;  // 144 p's per block
constexpr int PPG    = PCHUNK / 16;    // 9 p's per 16-lane group

// Routing pass. NV = how many v-vectors feed the logits (0 -> uniform c=0.1).
// Block = (chunk, b): 16 lane-groups x 16 lanes; group g covers p = base+i*16+g
// (wave reads 4 consecutive p -> contiguous 2KB of W per d). Recompute
// u_hat[10] per (p, lane o) on the fly, softmax over D in-register, accumulate
// s partials in registers, LDS-reduce the 16 groups, write ONE 160-float
// partial per block (no atomics, no memset needed).
template <int NV>
__global__ __launch_bounds__(256, 8)
void route_kernel(const float* __restrict__ x, const float* __restrict__ W,
                  const float* __restrict__ v0, const float* __restrict__ v1,
                  float* __restrict__ part)
{
    const int tid   = threadIdx.x;
    const int g     = tid >> 4;          // lane-group (0..15)
    const int o     = tid & 15;          // output dim
    const int b     = blockIdx.x & 255;  // b fast-varying: all XCDs share W chunk
    const int chunk = blockIdx.x >> 8;
    const int pbase = chunk * PCHUNK + g;

    // preload v[b, d, o] (sum of provided v's: uv(v0)+uv(v1) = uv(v0+v1))
    float vr[DCAPS];
    if constexpr (NV >= 1) {
#pragma unroll
        for (int d = 0; d < DCAPS; ++d) {
            float t = v0[(b * DCAPS + d) * ODIM + o];
            if constexpr (NV == 2) t += v1[(b * DCAPS + d) * ODIM + o];
            vr[d] = t;
        }
    }

    float s_acc[DCAPS];
#pragma unroll
    for (int d = 0; d < DCAPS; ++d) s_acc[d] = 0.f;

    for (int i = 0; i < PPG; ++i) {
        const int p = pbase + i * 16;

        // x[b,p,0:8] -- same 32B for all 16 lanes of the group (L1 broadcast)
        const float4* xp = reinterpret_cast<const float4*>(x + ((size_t)b * PCAPS + p) * IDIM);
        const float4 xa = xp[0];
        const float4 xb = xp[1];

        // u_hat[d] for this lane's o: dot8(W[d,p,o,:], x[b,p,:])
        float uh[DCAPS];
#pragma unroll
        for (int d = 0; d < DCAPS; ++d) {
            const float4* wp = reinterpret_cast<const float4*>(
                W + (((size_t)d * PCAPS + p) * ODIM + o) * IDIM);
            const float4 wa = wp[0];
            const float4 wb = wp[1];
            float acc;
            acc = wa.x * xa.x;
            acc = fmaf(wa.y, xa.y, acc);
            acc = fmaf(wa.z, xa.z, acc);
            acc = fmaf(wa.w, xa.w, acc);
            acc = fmaf(wb.x, xb.x, acc);
            acc = fmaf(wb.y, xb.y, acc);
            acc = fmaf(wb.z, xb.z, acc);
            acc = fmaf(wb.w, xb.w, acc);
            uh[d] = acc;
        }

        float c[DCAPS];
        if constexpr (NV == 0) {
#pragma unroll
            for (int d = 0; d < DCAPS; ++d) c[d] = 0.1f;
        } else {
            // logits: b[d] = sum_o u_hat[d][o] * vr[d][o] (reduce over 16 lanes)
            float logit[DCAPS];
#pragma unroll
            for (int d = 0; d < DCAPS; ++d) {
                float t = uh[d] * vr[d];
                t += __shfl_xor(t, 1, 16);
                t += __shfl_xor(t, 2, 16);
                t += __shfl_xor(t, 4, 16);
                t += __shfl_xor(t, 8, 16);
                logit[d] = t;
            }
            float mx = logit[0];
#pragma unroll
            for (int d = 1; d < DCAPS; ++d) mx = fmaxf(mx, logit[d]);
            float ssum = 0.f;
#pragma unroll
            for (int d = 0; d < DCAPS; ++d) {
                c[d] = __expf(logit[d] - mx);
                ssum += c[d];
            }
            const float inv = 1.0f / ssum;
#pragma unroll
            for (int d = 0; d < DCAPS; ++d) c[d] *= inv;
        }

#pragma unroll
        for (int d = 0; d < DCAPS; ++d) s_acc[d] = fmaf(c[d], uh[d], s_acc[d]);
    }

    // block-level reduction across the 16 groups; +1 pad kills bank conflicts
    __shared__ float red[16][DCAPS * ODIM + 1];
#pragma unroll
    for (int d = 0; d < DCAPS; ++d) red[g][d * ODIM + o] = s_acc[d];
    __syncthreads();
    if (tid < DCAPS * ODIM) {
        float t = 0.f;
#pragma unroll
        for (int g2 = 0; g2 < 16; ++g2) t += red[g2][tid];
        part[(size_t)blockIdx.x * (DCAPS * ODIM) + tid] = t;
    }
}

// sum the SPLIT chunk-partials, then squash over O=16; one thread per (b,d)
__global__ __launch_bounds__(256)
void squash_kernel(const float* __restrict__ part, float* __restrict__ out)
{
    const int idx = blockIdx.x * 256 + threadIdx.x;
    if (idx >= BATCH * DCAPS) return;
    const int b = idx / DCAPS;
    const int d = idx % DCAPS;

    float4 a = make_float4(0, 0, 0, 0), b4 = a, c4 = a, d4 = a;
#pragma unroll
    for (int c = 0; c < SPLIT; ++c) {
        const float4* sp = reinterpret_cast<const float4*>(
            part + ((size_t)(c * BATCH + b) * DCAPS + d) * ODIM);
        float4 p0 = sp[0], p1 = sp[1], p2 = sp[2], p3 = sp[3];
        a.x += p0.x; a.y += p0.y; a.z += p0.z; a.w += p0.w;
        b4.x += p1.x; b4.y += p1.y; b4.z += p1.z; b4.w += p1.w;
        c4.x += p2.x; c4.y += p2.y; c4.z += p2.z; c4.w += p2.w;
        d4.x += p3.x; d4.y += p3.y; d4.z += p3.z; d4.w += p3.w;
    }

    float sq = a.x * a.x + a.y * a.y + a.z * a.z + a.w * a.w
             + b4.x * b4.x + b4.y * b4.y + b4.z * b4.z + b4.w * b4.w
             + c4.x * c4.x + c4.y * c4.y + c4.z * c4.z + c4.w * c4.w
             + d4.x * d4.x + d4.y * d4.y + d4.z * d4.z + d4.w * d4.w;
    const float scale = (sq / (1.0f + sq)) / sqrtf(sq + EPS_);
    a.x *= scale; a.y *= scale; a.z *= scale; a.w *= scale;
    b4.x *= scale; b4.y *= scale; b4.z *= scale; b4.w *= scale;
    c4.x *= scale; c4.y *= scale; c4.z *= scale; c4.w *= scale;
    d4.x *= scale; d4.y *= scale; d4.z *= scale; d4.w *= scale;
    float4* op = reinterpret_cast<float4*>(out + (size_t)idx * ODIM);
    op[0] = a; op[1] = b4; op[2] = c4; op[3] = d4;
}

} // namespace

extern "C" void kernel_launch(void* const* d_in, const int* in_sizes, int n_in,
                              void* d_out, int out_size, void* d_ws, size_t ws_size,
                              hipStream_t stream)
{
    const float* x = (const float*)d_in[0];   // [256, 1152, 8]
    const float* W = (const float*)d_in[1];   // [1, 10, 1152, 16, 8]
    float* out = (float*)d_out;               // [256, 10, 16]

    constexpr size_t SDO = (size_t)BATCH * DCAPS * ODIM;  // 40960
    float* v0   = (float*)d_ws;
    float* v1   = v0 + SDO;
    float* part = v1 + SDO;                   // SPLIT * SDO floats (1.31 MB)

    const dim3 blk(256);
    const dim3 rgrid(SPLIT * BATCH);                   // 2048
    const dim3 sgrid((BATCH * DCAPS + 255) / 256);     // 10

    // pass 0: c uniform 0.1 -> s0 -> v0
    route_kernel<0><<<rgrid, blk, 0, stream>>>(x, W, nullptr, nullptr, part);
    squash_kernel<<<sgrid, blk, 0, stream>>>(part, v0);

    // pass 1: logits = uv(v0) -> s1 -> v1
    route_kernel<1><<<rgrid, blk, 0, stream>>>(x, W, v0, nullptr, part);
    squash_kernel<<<sgrid, blk, 0, stream>>>(part, v1);

    // pass 2: logits = uv(v0)+uv(v1) = uv(v0+v1) -> s2 -> out
    route_kernel<2><<<rgrid, blk, 0, stream>>>(x, W, v0, v1, part);
    squash_kernel<<<sgrid, blk, 0, stream>>>(part, out);
}

// Round 3
// 337.576 us; speedup vs baseline: 1.2108x; 1.2108x over previous
//
#include <hip/hip_runtime.h>

namespace {

constexpr int BATCH = 256;
constexpr int DCAPS = 10;
constexpr int PCAPS = 1152;
constexpr int ODIM  = 16;
constexpr int IDIM  = 8;
constexpr float EPS_ = 1e-7f;

constexpr int SPLIT  = 8;              // P-chunks (also partial-sum count)
constexpr int PCHUNK = PCAPS / SPLIT;  // 144 p's per block
constexpr int PPG    = PCHUNK / 16;    // 9 p's per 16-lane group

// Routing pass. NV = how many v-vectors feed the logits (0 -> uniform c=0.1).
// Block = (chunk, b): 16 lane-groups x 16 lanes; group g covers p = base+i*16+g
// (wave reads 4 consecutive p -> contiguous 2KB of W per d). Recompute
// u_hat[10] per (p, lane o) on the fly, softmax over D in-register, accumulate
// s partials in registers, LDS-reduce the 16 groups, write ONE 160-float
// partial per block (no atomics, no memset needed).
//
// launch_bounds: (256, 4) = VGPR cap 128. DO NOT use (256, 8): it caps VGPR
// at 32 < the ~56-reg live set -> scratch spills -> 490 MB/pass HBM traffic
// (R2 post-mortem: WRITE_SIZE 142 MB, dur 153 us).
template <int NV>
__global__ __launch_bounds__(256, 4)
void route_kernel(const float* __restrict__ x, const float* __restrict__ W,
                  const float* __restrict__ v0, const float* __restrict__ v1,
                  float* __restrict__ part)
{
    const int tid   = threadIdx.x;
    const int g     = tid >> 4;          // lane-group (0..15)
    const int o     = tid & 15;          // output dim
    const int b     = blockIdx.x & 255;  // b fast-varying: XCD-mates share W chunk
    const int chunk = blockIdx.x >> 8;
    const int pbase = chunk * PCHUNK + g;

    // preload v[b, d, o] (sum of provided v's: uv(v0)+uv(v1) = uv(v0+v1))
    float vr[DCAPS];
    if constexpr (NV >= 1) {
#pragma unroll
        for (int d = 0; d < DCAPS; ++d) {
            float t = v0[(b * DCAPS + d) * ODIM + o];
            if constexpr (NV == 2) t += v1[(b * DCAPS + d) * ODIM + o];
            vr[d] = t;
        }
    }

    float s_acc[DCAPS];
#pragma unroll
    for (int d = 0; d < DCAPS; ++d) s_acc[d] = 0.f;

    for (int i = 0; i < PPG; ++i) {
        const int p = pbase + i * 16;

        // x[b,p,0:8] -- same 32B for all 16 lanes of the group (L1 broadcast)
        const float4* xp = reinterpret_cast<const float4*>(x + ((size_t)b * PCAPS + p) * IDIM);
        const float4 xa = xp[0];
        const float4 xb = xp[1];

        // u_hat[d] for this lane's o: dot8(W[d,p,o,:], x[b,p,:])
        float uh[DCAPS];
#pragma unroll
        for (int d = 0; d < DCAPS; ++d) {
            const float4* wp = reinterpret_cast<const float4*>(
                W + (((size_t)d * PCAPS + p) * ODIM + o) * IDIM);
            const float4 wa = wp[0];
            const float4 wb = wp[1];
            float acc;
            acc = wa.x * xa.x;
            acc = fmaf(wa.y, xa.y, acc);
            acc = fmaf(wa.z, xa.z, acc);
            acc = fmaf(wa.w, xa.w, acc);
            acc = fmaf(wb.x, xb.x, acc);
            acc = fmaf(wb.y, xb.y, acc);
            acc = fmaf(wb.z, xb.z, acc);
            acc = fmaf(wb.w, xb.w, acc);
            uh[d] = acc;
        }

        float c[DCAPS];
        if constexpr (NV == 0) {
#pragma unroll
            for (int d = 0; d < DCAPS; ++d) c[d] = 0.1f;
        } else {
            // logits: b[d] = sum_o u_hat[d][o] * vr[d][o] (reduce over 16 lanes)
            float logit[DCAPS];
#pragma unroll
            for (int d = 0; d < DCAPS; ++d) {
                float t = uh[d] * vr[d];
                t += __shfl_xor(t, 1, 16);
                t += __shfl_xor(t, 2, 16);
                t += __shfl_xor(t, 4, 16);
                t += __shfl_xor(t, 8, 16);
                logit[d] = t;
            }
            float mx = logit[0];
#pragma unroll
            for (int d = 1; d < DCAPS; ++d) mx = fmaxf(mx, logit[d]);
            float ssum = 0.f;
#pragma unroll
            for (int d = 0; d < DCAPS; ++d) {
                c[d] = __expf(logit[d] - mx);
                ssum += c[d];
            }
            const float inv = 1.0f / ssum;
#pragma unroll
            for (int d = 0; d < DCAPS; ++d) c[d] *= inv;
        }

#pragma unroll
        for (int d = 0; d < DCAPS; ++d) s_acc[d] = fmaf(c[d], uh[d], s_acc[d]);
    }

    // block-level reduction across the 16 groups; +1 pad kills bank conflicts
    __shared__ float red[16][DCAPS * ODIM + 1];
#pragma unroll
    for (int d = 0; d < DCAPS; ++d) red[g][d * ODIM + o] = s_acc[d];
    __syncthreads();
    if (tid < DCAPS * ODIM) {
        float t = 0.f;
#pragma unroll
        for (int g2 = 0; g2 < 16; ++g2) t += red[g2][tid];
        part[(size_t)blockIdx.x * (DCAPS * ODIM) + tid] = t;
    }
}

// sum the SPLIT chunk-partials, then squash over O=16; one thread per (b,d)
__global__ __launch_bounds__(64)
void squash_kernel(const float* __restrict__ part, float* __restrict__ out)
{
    const int idx = blockIdx.x * 64 + threadIdx.x;
    if (idx >= BATCH * DCAPS) return;
    const int b = idx / DCAPS;
    const int d = idx % DCAPS;

    float4 a = make_float4(0, 0, 0, 0), b4 = a, c4 = a, d4 = a;
#pragma unroll
    for (int c = 0; c < SPLIT; ++c) {
        const float4* sp = reinterpret_cast<const float4*>(
            part + ((size_t)(c * BATCH + b) * DCAPS + d) * ODIM);
        float4 p0 = sp[0], p1 = sp[1], p2 = sp[2], p3 = sp[3];
        a.x += p0.x; a.y += p0.y; a.z += p0.z; a.w += p0.w;
        b4.x += p1.x; b4.y += p1.y; b4.z += p1.z; b4.w += p1.w;
        c4.x += p2.x; c4.y += p2.y; c4.z += p2.z; c4.w += p2.w;
        d4.x += p3.x; d4.y += p3.y; d4.z += p3.z; d4.w += p3.w;
    }

    float sq = a.x * a.x + a.y * a.y + a.z * a.z + a.w * a.w
             + b4.x * b4.x + b4.y * b4.y + b4.z * b4.z + b4.w * b4.w
             + c4.x * c4.x + c4.y * c4.y + c4.z * c4.z + c4.w * c4.w
             + d4.x * d4.x + d4.y * d4.y + d4.z * d4.z + d4.w * d4.w;
    const float scale = (sq / (1.0f + sq)) / sqrtf(sq + EPS_);
    a.x *= scale; a.y *= scale; a.z *= scale; a.w *= scale;
    b4.x *= scale; b4.y *= scale; b4.z *= scale; b4.w *= scale;
    c4.x *= scale; c4.y *= scale; c4.z *= scale; c4.w *= scale;
    d4.x *= scale; d4.y *= scale; d4.z *= scale; d4.w *= scale;
    float4* op = reinterpret_cast<float4*>(out + (size_t)idx * ODIM);
    op[0] = a; op[1] = b4; op[2] = c4; op[3] = d4;
}

} // namespace

extern "C" void kernel_launch(void* const* d_in, const int* in_sizes, int n_in,
                              void* d_out, int out_size, void* d_ws, size_t ws_size,
                              hipStream_t stream)
{
    const float* x = (const float*)d_in[0];   // [256, 1152, 8]
    const float* W = (const float*)d_in[1];   // [1, 10, 1152, 16, 8]
    float* out = (float*)d_out;               // [256, 10, 16]

    constexpr size_t SDO = (size_t)BATCH * DCAPS * ODIM;  // 40960
    float* v0   = (float*)d_ws;
    float* v1   = v0 + SDO;
    float* part = v1 + SDO;                   // SPLIT * SDO floats (1.31 MB)

    const dim3 blk(256);
    const dim3 rgrid(SPLIT * BATCH);                   // 2048
    const dim3 sblk(64);
    const dim3 sgrid((BATCH * DCAPS + 63) / 64);       // 40

    // pass 0: c uniform 0.1 -> s0 -> v0
    route_kernel<0><<<rgrid, blk, 0, stream>>>(x, W, nullptr, nullptr, part);
    squash_kernel<<<sgrid, sblk, 0, stream>>>(part, v0);

    // pass 1: logits = uv(v0) -> s1 -> v1
    route_kernel<1><<<rgrid, blk, 0, stream>>>(x, W, v0, nullptr, part);
    squash_kernel<<<sgrid, sblk, 0, stream>>>(part, v1);

    // pass 2: logits = uv(v0)+uv(v1) = uv(v0+v1) -> s2 -> out
    route_kernel<2><<<rgrid, blk, 0, stream>>>(x, W, v0, v1, part);
    squash_kernel<<<sgrid, sblk, 0, stream>>>(part, out);
}

// Round 5
// 251.366 us; speedup vs baseline: 1.6260x; 1.3430x over previous
//
#include <hip/hip_runtime.h>

namespace {

constexpr int BATCH = 256;
constexpr int DCAPS = 10;
constexpr int PCAPS = 1152;
constexpr int ODIM  = 16;
constexpr int IDIM  = 8;
constexpr float EPS_ = 1e-7f;

constexpr int NPBLK = 128;             // p-blocks (path-A partial count)
constexpr int PPB   = PCAPS / NPBLK;   // 9 p's per block, SHARED by all groups
constexpr int BBLK  = 16;              // b's per block (one per 16-lane group)
constexpr int NBB   = BATCH / BBLK;    // 16
constexpr int SDO   = BATCH * DCAPS * ODIM;  // 40960
constexpr int NSC   = 8;               // path-B super-chunks (atomic fallback)

// Routing pass. NV = number of v-vectors feeding logits (0 -> uniform 0.1).
// Block = (bBlk, pBlk): 16 lane-groups = 16 DIFFERENT b's, lane = o. All
// groups iterate the SAME p (R1's pattern: one W line serves 16 groups, W
// per block = 46 KB -> L1-resident). bBlk-major index => XCD = pBlk%8 under
// round-robin dispatch: each XCD's L2 sees only 16 pBlks (737 KB of W).
// No LDS, no atomics (path A): each group stores its own 160-float partial.
//
// launch_bounds (256,4): VGPR cap 128. (256,8) caps at 32 -> spills ->
// 490 MB/pass scratch traffic (R2: WRITE_SIZE 142 MB, 153 us). ~60 VGPR
// gives 8 waves/SIMD naturally.
template <int NV, bool ATOM>
__global__ __launch_bounds__(256, 4)
void route_kernel(const float* __restrict__ x, const float* __restrict__ W,
                  const float* __restrict__ v0, const float* __restrict__ v1,
                  float* __restrict__ part)
{
    const int tid  = threadIdx.x;
    const int g    = tid >> 4;             // lane-group (0..15) -> b
    const int o    = tid & 15;             // output dim
    const int pBlk = blockIdx.x % NPBLK;   // consecutive blocks differ in pBlk
    const int bBlk = blockIdx.x / NPBLK;
    const int b    = bBlk * BBLK + g;
    const int p0   = pBlk * PPB;

    // preload v[b,d,o] (sum of provided v's: uv(v0)+uv(v1) = uv(v0+v1))
    float vr[DCAPS];
    if constexpr (NV >= 1) {
#pragma unroll
        for (int d = 0; d < DCAPS; ++d) {
            float t = v0[(b * DCAPS + d) * ODIM + o];
            if constexpr (NV == 2) t += v1[(b * DCAPS + d) * ODIM + o];
            vr[d] = t;
        }
    }

    float s_acc[DCAPS];
#pragma unroll
    for (int d = 0; d < DCAPS; ++d) s_acc[d] = 0.f;

    for (int i = 0; i < PPB; ++i) {
        const int p = p0 + i;

        // x[b,p,0:8] -- same 32B for all 16 lanes of the group (L1 broadcast)
        const float4* xp = reinterpret_cast<const float4*>(x + ((size_t)b * PCAPS + p) * IDIM);
        const float4 xa = xp[0];
        const float4 xb = xp[1];

        // u_hat[d] for this lane's o: dot8(W[d,p,o,:], x[b,p,:]).
        // Same (d,p) for ALL groups -> wave reads 512B, block reuses via L1.
        float uh[DCAPS];
#pragma unroll
        for (int d = 0; d < DCAPS; ++d) {
            const float4* wp = reinterpret_cast<const float4*>(
                W + (((size_t)d * PCAPS + p) * ODIM + o) * IDIM);
            const float4 wa = wp[0];
            const float4 wb = wp[1];
            float acc;
            acc = wa.x * xa.x;
            acc = fmaf(wa.y, xa.y, acc);
            acc = fmaf(wa.z, xa.z, acc);
            acc = fmaf(wa.w, xa.w, acc);
            acc = fmaf(wb.x, xb.x, acc);
            acc = fmaf(wb.y, xb.y, acc);
            acc = fmaf(wb.z, xb.z, acc);
            acc = fmaf(wb.w, xb.w, acc);
            uh[d] = acc;
        }

        float c[DCAPS];
        if constexpr (NV == 0) {
#pragma unroll
            for (int d = 0; d < DCAPS; ++d) c[d] = 0.1f;
        } else {
            // logits: b[d] = sum_o u_hat[d][o]*vr[d][o] (reduce over 16 lanes)
            float logit[DCAPS];
#pragma unroll
            for (int d = 0; d < DCAPS; ++d) {
                float t = uh[d] * vr[d];
                t += __shfl_xor(t, 1, 16);
                t += __shfl_xor(t, 2, 16);
                t += __shfl_xor(t, 4, 16);
                t += __shfl_xor(t, 8, 16);
                logit[d] = t;
            }
            float mx = logit[0];
#pragma unroll
            for (int d = 1; d < DCAPS; ++d) mx = fmaxf(mx, logit[d]);
            float ssum = 0.f;
#pragma unroll
            for (int d = 0; d < DCAPS; ++d) {
                c[d] = __expf(logit[d] - mx);
                ssum += c[d];
            }
            const float inv = 1.0f / ssum;
#pragma unroll
            for (int d = 0; d < DCAPS; ++d) c[d] *= inv;
        }

#pragma unroll
        for (int d = 0; d < DCAPS; ++d) s_acc[d] = fmaf(c[d], uh[d], s_acc[d]);
    }

    if constexpr (ATOM) {
        // path B: fold into NSC super-chunks (16 adds per address)
#pragma unroll
        for (int d = 0; d < DCAPS; ++d)
            atomicAdd(&part[(((pBlk & (NSC - 1)) * BATCH + b) * DCAPS + d) * ODIM + o],
                      s_acc[d]);
    } else {
        // path A: private partial per (pBlk, b) -- deterministic, no races
#pragma unroll
        for (int d = 0; d < DCAPS; ++d)
            part[(((size_t)pBlk * BATCH + b) * DCAPS + d) * ODIM + o] = s_acc[d];
    }
}

// Sum NP chunk-partials then squash over O=16.
// Block: 256 threads = 8 chunk-groups (cg) x 32 output units (b*10+d).
// Per chunk the 32 units' 64B are contiguous -> coalesced; LDS tree over cg.
template <int NP>
__global__ __launch_bounds__(256)
void squash_kernel(const float* __restrict__ part, float* __restrict__ out)
{
    constexpr int CG  = 8;
    constexpr int CPC = NP / CG;            // chunks per cg-thread
    const int tid = threadIdx.x;
    const int cg  = tid >> 5;               // 0..7
    const int u   = tid & 31;               // unit within block
    const int gu  = blockIdx.x * 32 + u;    // global unit = b*DCAPS + d

    float4 a = make_float4(0, 0, 0, 0), b4 = a, c4 = a, d4 = a;
    for (int k = 0; k < CPC; ++k) {
        const int c = cg * CPC + k;
        const float4* sp = reinterpret_cast<const float4*>(
            part + (size_t)c * SDO + (size_t)gu * ODIM);
        float4 p0 = sp[0], p1 = sp[1], p2 = sp[2], p3 = sp[3];
        a.x += p0.x; a.y += p0.y; a.z += p0.z; a.w += p0.w;
        b4.x += p1.x; b4.y += p1.y; b4.z += p1.z; b4.w += p1.w;
        c4.x += p2.x; c4.y += p2.y; c4.z += p2.z; c4.w += p2.w;
        d4.x += p3.x; d4.y += p3.y; d4.z += p3.z; d4.w += p3.w;
    }

    __shared__ float red[CG][32][ODIM + 1];   // +1 pad: lanes stride 17 -> no conflicts
    float* r = red[cg][u];
    r[0]  = a.x;  r[1]  = a.y;  r[2]  = a.z;  r[3]  = a.w;
    r[4]  = b4.x; r[5]  = b4.y; r[6]  = b4.z; r[7]  = b4.w;
    r[8]  = c4.x; r[9]  = c4.y; r[10] = c4.z; r[11] = c4.w;
    r[12] = d4.x; r[13] = d4.y; r[14] = d4.z; r[15] = d4.w;
    __syncthreads();

    if (cg == 0) {
        float s[ODIM];
#pragma unroll
        for (int e = 0; e < ODIM; ++e) s[e] = red[0][u][e];
#pragma unroll
        for (int c2 = 1; c2 < CG; ++c2)
#pragma unroll
            for (int e = 0; e < ODIM; ++e) s[e] += red[c2][u][e];

        float sq = 0.f;
#pragma unroll
        for (int e = 0; e < ODIM; ++e) sq = fmaf(s[e], s[e], sq);
        const float scale = (sq / (1.0f + sq)) / sqrtf(sq + EPS_);
#pragma unroll
        for (int e = 0; e < ODIM; ++e) out[(size_t)gu * ODIM + e] = s[e] * scale;
    }
}

} // namespace

extern "C" void kernel_launch(void* const* d_in, const int* in_sizes, int n_in,
                              void* d_out, int out_size, void* d_ws, size_t ws_size,
                              hipStream_t stream)
{
    const float* x = (const float*)d_in[0];   // [256, 1152, 8]
    const float* W = (const float*)d_in[1];   // [1, 10, 1152, 16, 8]
    float* out = (float*)d_out;               // [256, 10, 16]

    float* v0   = (float*)d_ws;
    float* v1   = v0 + SDO;
    float* part = v1 + SDO;

    const dim3 blk(256);
    const dim3 rgrid(NPBLK * NBB);            // 2048
    const dim3 sgrid(BATCH * DCAPS / 32);     // 80

    const size_t needA = ((size_t)2 * SDO + (size_t)NPBLK * SDO) * sizeof(float); // ~21.3 MB

    if (ws_size >= needA) {
        // path A: private partials, fully deterministic
        route_kernel<0, false><<<rgrid, blk, 0, stream>>>(x, W, nullptr, nullptr, part);
        squash_kernel<NPBLK><<<sgrid, blk, 0, stream>>>(part, v0);

        route_kernel<1, false><<<rgrid, blk, 0, stream>>>(x, W, v0, nullptr, part);
        squash_kernel<NPBLK><<<sgrid, blk, 0, stream>>>(part, v1);

        route_kernel<2, false><<<rgrid, blk, 0, stream>>>(x, W, v0, v1, part);
        squash_kernel<NPBLK><<<sgrid, blk, 0, stream>>>(part, out);
    } else {
        // path B: atomic fallback into NSC super-chunks (1.3 MB, proven fit)
        const size_t pbytes = (size_t)NSC * SDO * sizeof(float);

        hipMemsetAsync(part, 0, pbytes, stream);
        route_kernel<0, true><<<rgrid, blk, 0, stream>>>(x, W, nullptr, nullptr, part);
        squash_kernel<NSC><<<sgrid, blk, 0, stream>>>(part, v0);

        hipMemsetAsync(part, 0, pbytes, stream);
        route_kernel<1, true><<<rgrid, blk, 0, stream>>>(x, W, v0, nullptr, part);
        squash_kernel<NSC><<<sgrid, blk, 0, stream>>>(part, v1);

        hipMemsetAsync(part, 0, pbytes, stream);
        route_kernel<2, true><<<rgrid, blk, 0, stream>>>(x, W, v0, v1, part);
        squash_kernel<NSC><<<sgrid, blk, 0, stream>>>(part, out);
    }
}

// Round 6
// 199.542 us; speedup vs baseline: 2.0483x; 1.2597x over previous
//
#include <hip/hip_runtime.h>

namespace {

constexpr int BATCH = 256;
constexpr int DCAPS = 10;
constexpr int PCAPS = 1152;
constexpr int ODIM  = 16;
constexpr int IDIM  = 8;
constexpr float EPS_ = 1e-7f;

constexpr int BT    = 64;              // b's per block (lane = b)
constexpr int NBB   = BATCH / BT;      // 4
constexpr int NPBLK = 128;             // p-blocks -> 21 MB partials (R5-proven fit)
constexpr int PPB   = PCAPS / NPBLK;   // 9 p's per block
constexpr int WAVES = 5;               // wave = d-pair (5 x 2 = D)
constexpr int XSTR  = PPB * IDIM + 1;  // 73: 73%32=9, gcd(9,32)=1 -> conflict-free
constexpr int SDO   = BATCH * DCAPS * ODIM;  // 40960

// Routing pass. Lane = b, wave = d-pair, o iterated in-lane.
// Key: W address depends only on (d,p,o) = wave-uniform (wid readfirstlane'd)
// -> compiler emits s_load (SMEM path), W bytes feed 64 b's each. This fixes
// R5's L1-bandwidth bound (22 x 1KB vector loads per p vs ~110 VALU ops).
// x staged in LDS per block; softmax over d via tiny LDS logit exchange.
//
// launch_bounds (320,4): VGPR cap 128 (live set ~115). (x,8) would cap at 64
// -> spills (R2 lesson: WRITE_SIZE exploded 28x, dur 2.2x).
template <int NV>
__global__ __launch_bounds__(320, 4)
void route_kernel(const float* __restrict__ x, const float* __restrict__ W,
                  const float* __restrict__ v0, const float* __restrict__ v1,
                  float* __restrict__ part)
{
    const int tid  = threadIdx.x;
    const int lane = tid & 63;
    const int wid  = __builtin_amdgcn_readfirstlane(tid >> 6);  // force SGPR
    const int d0   = 2 * wid;
    const int pBlk = blockIdx.x & (NPBLK - 1);   // pBlk fastest: RR over XCDs
    const int bBlk = blockIdx.x >> 7;
    const int b    = bBlk * BT + lane;
    const int p0   = pBlk * PPB;

    __shared__ float xs[BT][XSTR];       // 18.7 KB
    __shared__ float lx[DCAPS][BT];      // 2.5 KB logit exchange

    // ---- stage x[bTile, p0:p0+9, 0:8] into LDS (coalesced float4) ----
    for (int k = tid; k < BT * PPB * 2; k += 320) {       // 1152 float4
        const int bl = k / (PPB * 2);
        const int j  = k - bl * (PPB * 2);                 // pp*2 + half
        const int pp = j >> 1;
        const int ih = (j & 1) * 4;
        const float4 w4 = reinterpret_cast<const float4*>(x)[
            ((size_t)(bBlk * BT + bl) * PCAPS + p0 + pp) * 2 + (j & 1)];
        float* dst = &xs[bl][pp * IDIM + ih];
        dst[0] = w4.x; dst[1] = w4.y; dst[2] = w4.z; dst[3] = w4.w;
    }
    __syncthreads();

    // ---- preload v[b, d0:d0+2, :] (sum of v's: uv(v0)+uv(v1)=uv(v0+v1)) ----
    float vr[2][ODIM];
    if constexpr (NV >= 1) {
#pragma unroll
        for (int dd = 0; dd < 2; ++dd) {
            const float4* vp = reinterpret_cast<const float4*>(
                v0 + ((size_t)b * DCAPS + d0 + dd) * ODIM);
#pragma unroll
            for (int q = 0; q < 4; ++q) {
                float4 t = vp[q];
                if constexpr (NV == 2) {
                    const float4 u = reinterpret_cast<const float4*>(
                        v1 + ((size_t)b * DCAPS + d0 + dd) * ODIM)[q];
                    t.x += u.x; t.y += u.y; t.z += u.z; t.w += u.w;
                }
                vr[dd][q * 4 + 0] = t.x; vr[dd][q * 4 + 1] = t.y;
                vr[dd][q * 4 + 2] = t.z; vr[dd][q * 4 + 3] = t.w;
            }
        }
    }

    float s_acc[2][ODIM];
#pragma unroll
    for (int dd = 0; dd < 2; ++dd)
#pragma unroll
        for (int o = 0; o < ODIM; ++o) s_acc[dd][o] = 0.f;

    for (int pp = 0; pp < PPB; ++pp) {
        // x[b, p, 0:8] from LDS (conflict-free: row stride 73)
        float xr[IDIM];
#pragma unroll
        for (int i = 0; i < IDIM; ++i) xr[i] = xs[lane][pp * IDIM + i];

        // u_hat[d0+dd][o] = dot8(W[d,p,o,:], x) -- W via scalar loads
        float uh[2][ODIM];
#pragma unroll
        for (int dd = 0; dd < 2; ++dd) {
            const float4* wp4 = reinterpret_cast<const float4*>(
                W + (((size_t)(d0 + dd) * PCAPS + p0 + pp) * ODIM) * IDIM);
#pragma unroll
            for (int o = 0; o < ODIM; ++o) {
                const float4 wa = wp4[o * 2 + 0];
                const float4 wb = wp4[o * 2 + 1];
                float acc;
                acc = wa.x * xr[0];
                acc = fmaf(wa.y, xr[1], acc);
                acc = fmaf(wa.z, xr[2], acc);
                acc = fmaf(wa.w, xr[3], acc);
                acc = fmaf(wb.x, xr[4], acc);
                acc = fmaf(wb.y, xr[5], acc);
                acc = fmaf(wb.z, xr[6], acc);
                acc = fmaf(wb.w, xr[7], acc);
                uh[dd][o] = acc;
            }
        }

        if constexpr (NV == 0) {
#pragma unroll
            for (int dd = 0; dd < 2; ++dd)
#pragma unroll
                for (int o = 0; o < ODIM; ++o)
                    s_acc[dd][o] = fmaf(0.1f, uh[dd][o], s_acc[dd][o]);
        } else {
            // logits for this wave's two d's (in-lane dot over o)
            float l2[2];
#pragma unroll
            for (int dd = 0; dd < 2; ++dd) {
                float t = uh[dd][0] * vr[dd][0];
#pragma unroll
                for (int o = 1; o < ODIM; ++o) t = fmaf(uh[dd][o], vr[dd][o], t);
                l2[dd] = t;
            }
            // exchange: need max & denom over ALL 10 d's per b
            lx[d0 + 0][lane] = l2[0];
            lx[d0 + 1][lane] = l2[1];
            __syncthreads();
            float lv[DCAPS];
#pragma unroll
            for (int d = 0; d < DCAPS; ++d) lv[d] = lx[d][lane];
            __syncthreads();   // protect next iteration's writes
            float mx = lv[0];
#pragma unroll
            for (int d = 1; d < DCAPS; ++d) mx = fmaxf(mx, lv[d]);
            float den = 0.f;
#pragma unroll
            for (int d = 0; d < DCAPS; ++d) den += __expf(lv[d] - mx);
            const float inv = 1.0f / den;
#pragma unroll
            for (int dd = 0; dd < 2; ++dd) {
                const float c = __expf(l2[dd] - mx) * inv;
#pragma unroll
                for (int o = 0; o < ODIM; ++o)
                    s_acc[dd][o] = fmaf(c, uh[dd][o], s_acc[dd][o]);
            }
        }
    }

    // partial store: part[pBlk][bBlk][d][lane][o], coalesced dwordx4
#pragma unroll
    for (int dd = 0; dd < 2; ++dd) {
        float* dst = part + ((((size_t)pBlk * NBB + bBlk) * DCAPS + d0 + dd) * BT
                             + lane) * ODIM;
#pragma unroll
        for (int q = 0; q < 4; ++q) {
            float4 t;
            t.x = s_acc[dd][q * 4 + 0]; t.y = s_acc[dd][q * 4 + 1];
            t.z = s_acc[dd][q * 4 + 2]; t.w = s_acc[dd][q * 4 + 3];
            reinterpret_cast<float4*>(dst)[q] = t;
        }
    }
}

// Sum NPBLK chunk-partials then squash over O=16.
// Block: 256 threads = 8 chunk-groups (cg) x 32 output units (b*10+d).
__global__ __launch_bounds__(256)
void squash_kernel(const float* __restrict__ part, float* __restrict__ out)
{
    constexpr int CG  = 8;
    constexpr int CPC = NPBLK / CG;         // 16 chunks per cg-thread
    const int tid = threadIdx.x;
    const int cg  = tid >> 5;               // 0..7
    const int u   = tid & 31;
    const int gu  = blockIdx.x * 32 + u;    // b*DCAPS + d
    const int b   = gu / DCAPS;
    const int d   = gu - b * DCAPS;
    const int bb  = b >> 6;                 // bBlk
    const int bl  = b & 63;                 // lane within route block

    float4 a = make_float4(0, 0, 0, 0), b4 = a, c4 = a, d4 = a;
    for (int k = 0; k < CPC; ++k) {
        const int c = cg * CPC + k;
        const float4* sp = reinterpret_cast<const float4*>(
            part + ((((size_t)c * NBB + bb) * DCAPS + d) * BT + bl) * ODIM);
        float4 p0 = sp[0], p1 = sp[1], p2 = sp[2], p3 = sp[3];
        a.x += p0.x; a.y += p0.y; a.z += p0.z; a.w += p0.w;
        b4.x += p1.x; b4.y += p1.y; b4.z += p1.z; b4.w += p1.w;
        c4.x += p2.x; c4.y += p2.y; c4.z += p2.z; c4.w += p2.w;
        d4.x += p3.x; d4.y += p3.y; d4.z += p3.z; d4.w += p3.w;
    }

    __shared__ float red[CG][32][ODIM + 1];   // +1 pad -> no bank conflicts
    float* r = red[cg][u];
    r[0]  = a.x;  r[1]  = a.y;  r[2]  = a.z;  r[3]  = a.w;
    r[4]  = b4.x; r[5]  = b4.y; r[6]  = b4.z; r[7]  = b4.w;
    r[8]  = c4.x; r[9]  = c4.y; r[10] = c4.z; r[11] = c4.w;
    r[12] = d4.x; r[13] = d4.y; r[14] = d4.z; r[15] = d4.w;
    __syncthreads();

    if (cg == 0) {
        float s[ODIM];
#pragma unroll
        for (int e = 0; e < ODIM; ++e) s[e] = red[0][u][e];
#pragma unroll
        for (int c2 = 1; c2 < CG; ++c2)
#pragma unroll
            for (int e = 0; e < ODIM; ++e) s[e] += red[c2][u][e];

        float sq = 0.f;
#pragma unroll
        for (int e = 0; e < ODIM; ++e) sq = fmaf(s[e], s[e], sq);
        const float scale = (sq / (1.0f + sq)) / sqrtf(sq + EPS_);
#pragma unroll
        for (int e = 0; e < ODIM; ++e) out[(size_t)gu * ODIM + e] = s[e] * scale;
    }
}

} // namespace

extern "C" void kernel_launch(void* const* d_in, const int* in_sizes, int n_in,
                              void* d_out, int out_size, void* d_ws, size_t ws_size,
                              hipStream_t stream)
{
    const float* x = (const float*)d_in[0];   // [256, 1152, 8]
    const float* W = (const float*)d_in[1];   // [1, 10, 1152, 16, 8]
    float* out = (float*)d_out;               // [256, 10, 16]

    float* v0   = (float*)d_ws;
    float* v1   = v0 + SDO;
    float* part = v1 + SDO;                   // NPBLK * SDO floats (21 MB, R5-proven)

    const dim3 rblk(320);                     // 5 waves = 5 d-pairs
    const dim3 rgrid(NPBLK * NBB);            // 512
    const dim3 sblk(256);
    const dim3 sgrid(BATCH * DCAPS / 32);     // 80

    // pass 0: c uniform 0.1 -> s0 -> v0
    route_kernel<0><<<rgrid, rblk, 0, stream>>>(x, W, nullptr, nullptr, part);
    squash_kernel<<<sgrid, sblk, 0, stream>>>(part, v0);

    // pass 1: logits = uv(v0) -> s1 -> v1
    route_kernel<1><<<rgrid, rblk, 0, stream>>>(x, W, v0, nullptr, part);
    squash_kernel<<<sgrid, sblk, 0, stream>>>(part, v1);

    // pass 2: logits = uv(v0)+uv(v1) = uv(v0+v1) -> s2 -> out
    route_kernel<2><<<rgrid, rblk, 0, stream>>>(x, W, v0, v1, part);
    squash_kernel<<<sgrid, sblk, 0, stream>>>(part, out);
}